// Round 2
// baseline (928.922 us; speedup 1.0000x reference)
//
#include <hip/hip_runtime.h>
#include <cstdint>
#include <cstddef>

// Problem constants
#define Bsz   16384
#define INsz  10
#define Hsz   1024
#define N4    4096      // 4 gates * H
#define K2    1056      // H + IN padded to multiple of 32
#define SIXH  6144
#define GDI   7
#define LR    0.001f
#define NPART 512       // partial-grad blocks in gd pass

typedef _Float16 f16;
typedef __attribute__((ext_vector_type(8))) _Float16 f16x8;
typedef __attribute__((ext_vector_type(4))) _Float16 f16x4;
typedef __attribute__((ext_vector_type(4))) float    f32x4;

// async global->LDS, 16B per lane; LDS dest = wave-uniform base + lane*16.
__device__ __forceinline__ void llds16(const f16* g, f16* l) {
    __builtin_amdgcn_global_load_lds(
        (__attribute__((address_space(1))) void*)(uintptr_t)g,
        (__attribute__((address_space(3))) void*)(uintptr_t)l,
        16, 0, 0);
}

__device__ __forceinline__ float sigm(float z)   { return 1.f / (1.f + __expf(-z)); }
__device__ __forceinline__ float tanh_f(float z) { return 1.f - 2.f / (__expf(2.f * z) + 1.f); }

// ---------------------------------------------------------------------------
// U2[n][j] (fp16, [4096 x 1056]): j<1024 -> U_g[h][j]; 1024<=j<1034 -> W_g[h][j-1024]; else 0
__global__ void k_prepU(const float* __restrict__ Uf, const float* __restrict__ Ui,
                        const float* __restrict__ Uc, const float* __restrict__ Uo,
                        const float* __restrict__ Wf, const float* __restrict__ Wi,
                        const float* __restrict__ Wc, const float* __restrict__ Wo,
                        f16* __restrict__ U2) {
    int idx = blockIdx.x * 256 + threadIdx.x;      // N4*K2 threads
    int n = idx / K2;
    int j = idx - n * K2;
    int g = n >> 10, h = n & 1023;
    const float* U = (g == 0) ? Uf : (g == 1) ? Ui : (g == 2) ? Uc : Uo;
    const float* W = (g == 0) ? Wf : (g == 1) ? Wi : (g == 2) ? Wc : Wo;
    float v = 0.f;
    if (j < Hsz)              v = U[(size_t)h * Hsz + j];
    else if (j < Hsz + INsz)  v = W[h * INsz + (j - Hsz)];
    U2[idx] = (f16)v;
}

__global__ void k_zero(float* __restrict__ p, int n) {
    int i = blockIdx.x * 256 + threadIdx.x;
    if (i < n) p[i] = 0.f;
}

// ---------------------------------------------------------------------------
// GEMM: rt4[b, n] = sum_k [hidden|x][b,k] * U2[n,k] + bias_g[h]   (preactivations, fp16)
// 128x128 tile, BK=32, 256 threads (2x2 waves of 64x64), 16x16x32 MFMA.
// A staged from fp32 via register cvt + ds_write; B staged via global_load_lds.
__global__ __launch_bounds__(256, 2) void k_gemm(const float* __restrict__ hid,
                                                 const float* __restrict__ x,
                                                 const f16* __restrict__ U2,
                                                 const float* __restrict__ bf_,
                                                 const float* __restrict__ bi_,
                                                 const float* __restrict__ bc_,
                                                 const float* __restrict__ bo_,
                                                 f16* __restrict__ rt4) {
    __shared__ __align__(16) f16 As[128 * 32];
    __shared__ __align__(16) f16 Bs[128 * 32];
    const int tid  = threadIdx.x;
    const int bn   = blockIdx.x & 31;    // 32 n-tiles
    const int bm   = blockIdx.x >> 5;    // 128 m-tiles
    const int wave = tid >> 6, lane = tid & 63;
    const int wr = wave >> 1, wc = wave & 1;
    const int r = lane & 15, q = lane >> 4;

    const int arow = tid >> 2, acol = (tid & 3) * 8;
    const float* ga = hid + (size_t)(bm * 128 + arow) * Hsz + acol;
    const f16*   gb = U2  + (size_t)(bn * 128 + arow) * K2 + acol;
    f16* lB = &Bs[tid * 8];

    f32x4 acc[4][4];
#pragma unroll
    for (int i = 0; i < 4; ++i)
#pragma unroll
        for (int j = 0; j < 4; ++j) acc[i][j] = (f32x4){0.f, 0.f, 0.f, 0.f};

    for (int kt = 0; kt < K2; kt += 32) {
        float a0[8], a1[8];
        if (kt < Hsz) {
            float4 t0 = *(const float4*)(ga + kt);
            float4 t1 = *(const float4*)(ga + kt + 4);
            float4 t2 = *(const float4*)(ga + kt + (size_t)64 * Hsz);
            float4 t3 = *(const float4*)(ga + kt + (size_t)64 * Hsz + 4);
            a0[0]=t0.x; a0[1]=t0.y; a0[2]=t0.z; a0[3]=t0.w;
            a0[4]=t1.x; a0[5]=t1.y; a0[6]=t1.z; a0[7]=t1.w;
            a1[0]=t2.x; a1[1]=t2.y; a1[2]=t2.z; a1[3]=t2.w;
            a1[4]=t3.x; a1[5]=t3.y; a1[6]=t3.z; a1[7]=t3.w;
        } else {            // K-extension: [x(10) | zeros(22)]
#pragma unroll
            for (int k = 0; k < 8; ++k) {
                int c = acol + k;
                a0[k] = (c < INsz) ? x[(size_t)(bm * 128 + arow) * INsz + c] : 0.f;
                a1[k] = (c < INsz) ? x[(size_t)(bm * 128 + arow + 64) * INsz + c] : 0.f;
            }
        }
        __syncthreads();                       // prev iter's LDS reads done
        llds16(gb + kt,                   lB);
        llds16(gb + kt + (size_t)64 * K2, lB + 2048);
        f16x8 h0, h1;
#pragma unroll
        for (int k = 0; k < 8; ++k) { h0[k] = (f16)a0[k]; h1[k] = (f16)a1[k]; }
        *(f16x8*)&As[tid * 8]        = h0;
        *(f16x8*)&As[tid * 8 + 2048] = h1;
        __syncthreads();                       // staging complete

        f16x8 af[4], bf[4];
#pragma unroll
        for (int i = 0; i < 4; ++i)
            af[i] = *(const f16x8*)&As[(wr * 64 + i * 16 + r) * 32 + q * 8];
#pragma unroll
        for (int j = 0; j < 4; ++j)
            bf[j] = *(const f16x8*)&Bs[(wc * 64 + j * 16 + r) * 32 + q * 8];
#pragma unroll
        for (int i = 0; i < 4; ++i)
#pragma unroll
            for (int j = 0; j < 4; ++j)
                acc[i][j] = __builtin_amdgcn_mfma_f32_16x16x32_f16(af[i], bf[j], acc[i][j], 0, 0, 0);
    }

    // bias + store preactivations. C/D layout: col = lane&15, row = (lane>>4)*4 + reg
    const int g = bn >> 3;
    const int h_base = (bn & 7) * 128;
    const float* Bb = (g == 0) ? bf_ : (g == 1) ? bi_ : (g == 2) ? bc_ : bo_;
    float bias[4];
#pragma unroll
    for (int j = 0; j < 4; ++j) bias[j] = Bb[h_base + wc * 64 + j * 16 + r];
#pragma unroll
    for (int i = 0; i < 4; ++i)
#pragma unroll
        for (int j = 0; j < 4; ++j)
#pragma unroll
            for (int reg = 0; reg < 4; ++reg) {
                int row_l = wr * 64 + i * 16 + q * 4 + reg;
                int col_l = wc * 64 + j * 16 + r;
                rt4[(size_t)(bm * 128 + row_l) * N4 + bn * 128 + col_l]
                    = (f16)(acc[i][j][reg] + bias[j]);
            }
}

// ---------------------------------------------------------------------------
// In-place activation epilogue; c_new (fp32) -> out_c.  h_std not stored.
__global__ void k_epi(f16* __restrict__ rt4, const float* __restrict__ c,
                      float* __restrict__ c_out) {
    int idx = blockIdx.x * 256 + threadIdx.x;  // Bsz*Hsz threads
    int b = idx >> 10, h = idx & 1023;
    size_t zb = (size_t)b * N4 + h;
    float f  = sigm((float)rt4[zb]);
    float i_ = sigm((float)rt4[zb + 1024]);
    float ct = tanh_f((float)rt4[zb + 2048]);
    float o  = sigm((float)rt4[zb + 3072]);
    float cn = f * c[idx] + i_ * ct;
    rt4[zb]        = (f16)f;
    rt4[zb + 1024] = (f16)i_;
    rt4[zb + 2048] = (f16)ct;
    rt4[zb + 3072] = (f16)o;
    c_out[idx] = cn;
}

// ---------------------------------------------------------------------------
// Fused GD iteration: one pass over rt4 + c_new. Block = 256 threads, 32 rows.
// Features: [0,4096) = rt4 (f,i,ct,o); [4096,5120) = c_new (fp32); [5120,6144) = h_std
// (recomputed = o * tanh(cn)). Thread t owns cols {t*8}, {2048+t*8}, cn {t*4}, hs {t*4}.
__global__ __launch_bounds__(256) void k_gd(const f16* __restrict__ rt4,
                                            const float* __restrict__ cn,
                                            const float* __restrict__ mp,
                                            const float* __restrict__ theta,
                                            float* __restrict__ part) {
    const int tid = threadIdx.x;
    const int r0 = blockIdx.x * 32;
    const int wave = tid >> 6, lane = tid & 63;

    float thA[8], thB[8], thC[4], thD[4];
    float grA[8] = {0}, grB[8] = {0}, grC[4] = {0}, grD[4] = {0};
#pragma unroll
    for (int k = 0; k < 8; ++k) {
        thA[k] = theta[tid * 8 + k];
        thB[k] = theta[2048 + tid * 8 + k];
    }
#pragma unroll
    for (int k = 0; k < 4; ++k) {
        thC[k] = theta[4096 + tid * 4 + k];
        thD[k] = theta[5120 + tid * 4 + k];
    }

    __shared__ float red[16];   // [rr][wave]

    for (int rb = 0; rb < 32; rb += 4) {
        f16x8 dA[4], dB[4];
        f32x4 dC[4];
        float hs[4][4];
        float s[4];
#pragma unroll
        for (int rr = 0; rr < 4; ++rr) {
            const size_t row = (size_t)(r0 + rb + rr);
            dA[rr] = *(const f16x8*)&rt4[row * N4 + tid * 8];
            dB[rr] = *(const f16x8*)&rt4[row * N4 + 2048 + tid * 8];
            dC[rr] = *(const f32x4*)&cn[row * Hsz + tid * 4];
            f16x4 dO = *(const f16x4*)&rt4[row * N4 + 3072 + tid * 4];
            float a = 0.f;
#pragma unroll
            for (int k = 0; k < 8; ++k) a += (float)dA[rr][k] * thA[k];
#pragma unroll
            for (int k = 0; k < 8; ++k) a += (float)dB[rr][k] * thB[k];
#pragma unroll
            for (int k = 0; k < 4; ++k) {
                float h = (float)dO[k] * tanh_f(dC[rr][k]);
                hs[rr][k] = h;
                a += dC[rr][k] * thC[k] + h * thD[k];
            }
            s[rr] = a;
        }
#pragma unroll
        for (int rr = 0; rr < 4; ++rr)
#pragma unroll
            for (int off = 32; off > 0; off >>= 1)
                s[rr] += __shfl_xor(s[rr], off, 64);
        if (lane == 0) {
#pragma unroll
            for (int rr = 0; rr < 4; ++rr) red[rr * 4 + wave] = s[rr];
        }
        __syncthreads();
        float e[4];
#pragma unroll
        for (int rr = 0; rr < 4; ++rr)
            e[rr] = (red[rr * 4 + 0] + red[rr * 4 + 1] + red[rr * 4 + 2] + red[rr * 4 + 3])
                    - mp[r0 + rb + rr];
        __syncthreads();
#pragma unroll
        for (int rr = 0; rr < 4; ++rr) {
#pragma unroll
            for (int k = 0; k < 8; ++k) {
                grA[k] += e[rr] * (float)dA[rr][k];
                grB[k] += e[rr] * (float)dB[rr][k];
            }
#pragma unroll
            for (int k = 0; k < 4; ++k) {
                grC[k] += e[rr] * dC[rr][k];
                grD[k] += e[rr] * hs[rr][k];
            }
        }
    }

    float* pb = &part[(size_t)blockIdx.x * SIXH];
#pragma unroll
    for (int k = 0; k < 8; ++k) {
        pb[tid * 8 + k]        = grA[k];
        pb[2048 + tid * 8 + k] = grB[k];
    }
#pragma unroll
    for (int k = 0; k < 4; ++k) {
        pb[4096 + tid * 4 + k] = grC[k];
        pb[5120 + tid * 4 + k] = grD[k];
    }
}

// Reduce NPART partial grads -> theta update (deterministic fixed-order sums).
__global__ void k_reduce(const float* __restrict__ part, float* __restrict__ theta) {
    __shared__ float sred[256];
    const int tid = threadIdx.x;
    const int c = (tid & 31) + blockIdx.x * 32;
    const int pl = tid >> 5;
    float s = 0.f;
    for (int p = pl; p < NPART; p += 8) s += part[(size_t)p * SIXH + c];
    sred[tid] = s;
    __syncthreads();
    if (pl == 0) {
        float acc = s;
#pragma unroll
        for (int k = 1; k < 8; ++k) acc += sred[k * 32 + (tid & 31)];
        theta[c] -= (2.f * LR / (float)Bsz) * acc;
    }
}

// ---------------------------------------------------------------------------
// argmax over per-gate mean|theta|; result (0..5) stored as float in out_c[0]
// (fixed-order reduction -> deterministic across runs).
__global__ void k_argmax(const float* __restrict__ theta, float* __restrict__ outc) {
    __shared__ float w[6][4];
    const int tid = threadIdx.x;   // 256
    const int wave = tid >> 6, lane = tid & 63;
    for (int g = 0; g < 6; ++g) {
        float s = 0.f;
        for (int j = tid; j < 1024; j += 256) s += fabsf(theta[g * 1024 + j]);
#pragma unroll
        for (int off = 32; off > 0; off >>= 1) s += __shfl_xor(s, off, 64);
        if (lane == 0) w[g][wave] = s;
    }
    __syncthreads();
    if (tid == 0) {
        int best = 0;
        float bv = w[0][0] + w[0][1] + w[0][2] + w[0][3];
        for (int g = 1; g < 6; ++g) {
            float v = w[g][0] + w[g][1] + w[g][2] + w[g][3];
            if (v > bv) { bv = v; best = g; }   // strict >: first max wins (matches argmax)
        }
        outc[0] = (float)best;
    }
}

// Gather h_new. Reads rt4 (ws) + out_c only; writes out_h only -> no race with
// the scratch that lived in out_h (all dead by now).
__global__ void k_gather(const f16* __restrict__ rt4, const float* __restrict__ cnp,
                         float* __restrict__ outh) {
    const int idx = (int)cnp[0];
    int t = blockIdx.x * 256 + threadIdx.x;   // Bsz*Hsz/4 threads
    int b = t >> 8, h4 = (t & 255) * 4;
    float* o = &outh[(size_t)b * Hsz + h4];
    if (idx < 4) {
        f16x4 v = *(const f16x4*)&rt4[(size_t)b * N4 + idx * 1024 + h4];
#pragma unroll
        for (int k = 0; k < 4; ++k) o[k] = (float)v[k];
    } else if (idx == 4) {
        f32x4 v = *(const f32x4*)&cnp[(size_t)b * Hsz + h4];
#pragma unroll
        for (int k = 0; k < 4; ++k) o[k] = v[k];
    } else {
        f16x4 ov = *(const f16x4*)&rt4[(size_t)b * N4 + 3072 + h4];
        f32x4 cv = *(const f32x4*)&cnp[(size_t)b * Hsz + h4];
#pragma unroll
        for (int k = 0; k < 4; ++k) o[k] = (float)ov[k] * tanh_f(cv[k]);
    }
}

// Restore c_new[0] (clobbered by the smuggled argmax index) and fix out_h[0]
// for the idx==4/5 paths that read the clobbered value.
__global__ void k_fix(const f16* __restrict__ rt4, const float* __restrict__ c_in,
                      float* __restrict__ out) {
    if (threadIdx.x == 0 && blockIdx.x == 0) {
        int idx = (int)out[(size_t)Bsz * Hsz];
        float f  = (float)rt4[0];
        float i_ = (float)rt4[1024];
        float ct = (float)rt4[2048];
        float o  = (float)rt4[3072];
        float cn = f * c_in[0] + i_ * ct;
        out[(size_t)Bsz * Hsz] = cn;
        if (idx == 4)      out[0] = cn;
        else if (idx == 5) out[0] = o * tanh_f(cn);
    }
}

// ---------------------------------------------------------------------------
extern "C" void kernel_launch(void* const* d_in, const int* in_sizes, int n_in,
                              void* d_out, int out_size, void* d_ws, size_t ws_size,
                              hipStream_t stream) {
    const float* x    = (const float*)d_in[0];
    const float* hid  = (const float*)d_in[1];
    const float* c    = (const float*)d_in[2];
    const float* mp   = (const float*)d_in[3];
    const float* Wf_w = (const float*)d_in[4];
    const float* Wf_b = (const float*)d_in[5];
    const float* Uf_w = (const float*)d_in[6];
    const float* Wi_w = (const float*)d_in[7];
    const float* Wi_b = (const float*)d_in[8];
    const float* Ui_w = (const float*)d_in[9];
    const float* Wc_w = (const float*)d_in[10];
    const float* Wc_b = (const float*)d_in[11];
    const float* Uc_w = (const float*)d_in[12];
    const float* Wo_w = (const float*)d_in[13];
    const float* Wo_b = (const float*)d_in[14];
    const float* Uo_w = (const float*)d_in[15];
    float* out  = (float*)d_out;                       // [h_new | c_new] fp32
    float* outc = out + (size_t)Bsz * Hsz;

    // ws: rt4 only — exactly 134,217,728 B (128 MiB)
    f16* rt4 = (f16*)d_ws;
    // scratch inside out's h_new half (dead before k_gather overwrites it):
    uint8_t* oh = (uint8_t*)d_out;
    f16*   U2    = (f16*)oh;                           // 4096*1056*2 = 8,650,752 B
    float* theta = (float*)(oh + 8650752);             // 24,576 B
    float* part  = (float*)(oh + 8675328);             // 512*6144*4 = 12,582,912 B (ends 21.3 MB < 64 MB)

    k_prepU<<<(N4 * K2) / 256, 256, 0, stream>>>(Uf_w, Ui_w, Uc_w, Uo_w,
                                                 Wf_w, Wi_w, Wc_w, Wo_w, U2);
    k_gemm<<<4096, 256, 0, stream>>>(hid, x, U2, Wf_b, Wi_b, Wc_b, Wo_b, rt4);
    k_epi<<<(Bsz * Hsz) / 256, 256, 0, stream>>>(rt4, c, outc);
    k_zero<<<24, 256, 0, stream>>>(theta, SIXH);
    for (int it = 0; it < GDI; ++it) {
        k_gd<<<NPART, 256, 0, stream>>>(rt4, outc, mp, theta, part);
        k_reduce<<<SIXH / 32, 256, 0, stream>>>(part, theta);
    }
    k_argmax<<<1, 256, 0, stream>>>(theta, outc);
    k_gather<<<(Bsz * Hsz / 4) / 256, 256, 0, stream>>>(rt4, outc, out);
    k_fix<<<1, 64, 0, stream>>>(rt4, c, out);
}